// Round 17
// baseline (176.614 us; speedup 1.0000x reference)
//
#include <hip/hip_runtime.h>

// Problem constants
#define B 4
#define S 8192
#define D 256
#define H 8
#define NT 128               // col-stat tiles per batch (kA), 64 rows each
#define LOG2E 1.4426950408889634f
#define E2(x) __builtin_amdgcn_exp2f(x)

// Workspace layout (float offsets)
#define WS_WQ    0
#define WS_WV    8
#define WS_QMAX  16
#define WS_QMIN  (WS_QMAX + B*D)
#define WS_CV    (WS_QMIN + B*D)
#define WS_ZACC  (WS_CV + B*D)          // B*H*D
#define WS_WP    (WS_ZACC + B*H*D)      // 1024 weight partials
#define WS_P1    (WS_WP + 1024)
#define WS_P2    (WS_P1 + B*NT*D)
#define WS_P3    (WS_P2 + B*NT*D)

// ---------------------------------------------------------------------------
// kA: blocks [0,512): per-tile col stats of q (max/min) and v (sum).
//     blocks [512,768): weight-chunk partial sums.  (R14-exact)
__global__ __launch_bounds__(256) void kA(const float* __restrict__ q,
                                          const float* __restrict__ v,
                                          const float* __restrict__ qw,
                                          const float* __restrict__ vw,
                                          float* __restrict__ ws) {
    const int blk = blockIdx.x;
    const int t = threadIdx.x, w = t >> 6, lane = t & 63;

    if (blk >= B * NT) {                       // weight partials
        const int i = blk - B * NT;            // 0..255: which=i>>7, h=(i>>4)&7, ch=i&15
        const float4* src = (const float4*)(((i >> 7) ? vw : qw)
                              + (size_t)((i >> 4) & 7) * D * D) + (i & 15) * 1024;
        float sm = 0.f;
        #pragma unroll
        for (int j = 0; j < 4; ++j) {
            float4 a4 = src[j * 256 + t];
            sm += (a4.x + a4.y) + (a4.z + a4.w);
        }
        #pragma unroll
        for (int off = 32; off; off >>= 1) sm += __shfl_down(sm, off, 64);
        if (lane == 0) ws[WS_WP + i * 4 + w] = sm;
        return;
    }

    const int b = blk >> 7, tl = blk & (NT - 1);
    const int g = lane >> 4, cl = lane & 15;
    const int cblk = w * 16 + cl;              // 16B col block, 0..63
    const float4* qbase = (const float4*)(q + ((size_t)b * S + tl * 64) * D);
    const float4* vbase = (const float4*)(v + ((size_t)b * S + tl * 64) * D);
    float4 qmx = make_float4(-3.4e38f, -3.4e38f, -3.4e38f, -3.4e38f);
    float4 qmn = make_float4(3.4e38f, 3.4e38f, 3.4e38f, 3.4e38f);
    float4 vs = make_float4(0.f, 0.f, 0.f, 0.f);
    #pragma unroll 4
    for (int i = 0; i < 16; ++i) {
        const int row = i * 4 + g;
        float4 a4 = qbase[row * 64 + cblk];
        qmx.x = fmaxf(qmx.x, a4.x); qmx.y = fmaxf(qmx.y, a4.y);
        qmx.z = fmaxf(qmx.z, a4.z); qmx.w = fmaxf(qmx.w, a4.w);
        qmn.x = fminf(qmn.x, a4.x); qmn.y = fminf(qmn.y, a4.y);
        qmn.z = fminf(qmn.z, a4.z); qmn.w = fminf(qmn.w, a4.w);
        float4 b4 = vbase[row * 64 + cblk];
        vs.x += b4.x; vs.y += b4.y; vs.z += b4.z; vs.w += b4.w;
    }
    #pragma unroll
    for (int off = 16; off <= 32; off <<= 1) {
        qmx.x = fmaxf(qmx.x, __shfl_xor(qmx.x, off, 64));
        qmx.y = fmaxf(qmx.y, __shfl_xor(qmx.y, off, 64));
        qmx.z = fmaxf(qmx.z, __shfl_xor(qmx.z, off, 64));
        qmx.w = fmaxf(qmx.w, __shfl_xor(qmx.w, off, 64));
        qmn.x = fminf(qmn.x, __shfl_xor(qmn.x, off, 64));
        qmn.y = fminf(qmn.y, __shfl_xor(qmn.y, off, 64));
        qmn.z = fminf(qmn.z, __shfl_xor(qmn.z, off, 64));
        qmn.w = fminf(qmn.w, __shfl_xor(qmn.w, off, 64));
        vs.x += __shfl_xor(vs.x, off, 64);
        vs.y += __shfl_xor(vs.y, off, 64);
        vs.z += __shfl_xor(vs.z, off, 64);
        vs.w += __shfl_xor(vs.w, off, 64);
    }
    if (g == 0) {
        size_t pi = (size_t)(b * NT + tl) * D + cblk * 4;
        *(float4*)&ws[WS_P1 + pi] = qmx;
        *(float4*)&ws[WS_P2 + pi] = qmn;
        *(float4*)&ws[WS_P3 + pi] = vs;
    }
}

// ---------------------------------------------------------------------------
// kB: blocks 0..31 finish col stats; block 32 finishes weight sums;
//     block 33 zeroes the Z accumulators.  (R14-exact)
__global__ __launch_bounds__(256) void kB(float* __restrict__ ws) {
    const int blk = blockIdx.x, t = threadIdx.x;
    if (blk < 32) {
        const int bb = blk >> 3, oct = blk & 7;
        const int dl = t >> 3, sub = t & 7;
        const int d = oct * 32 + dl;
        float mx = -3.4e38f, mn = 3.4e38f, sm = 0.f;
        #pragma unroll 4
        for (int i = 0; i < 16; ++i) {
            size_t idx = (size_t)(bb * NT + sub * 16 + i) * D + d;
            mx = fmaxf(mx, ws[WS_P1 + idx]);
            mn = fminf(mn, ws[WS_P2 + idx]);
            sm += ws[WS_P3 + idx];
        }
        #pragma unroll
        for (int off = 1; off < 8; off <<= 1) {
            mx = fmaxf(mx, __shfl_xor(mx, off, 64));
            mn = fminf(mn, __shfl_xor(mn, off, 64));
            sm += __shfl_xor(sm, off, 64);
        }
        if (sub == 0) {
            ws[WS_QMAX + bb * D + d] = mx;
            ws[WS_QMIN + bb * D + d] = mn;
            ws[WS_CV + bb * D + d] = sm * (float)D;
        }
    } else if (blk == 32) {
        const int o = t >> 4, j = t & 15;        // o: 0..15 = (which,h)
        float s = 0.f;
        #pragma unroll
        for (int ww = 0; ww < 4; ++ww) s += ws[WS_WP + (o * 16 + j) * 4 + ww];
        #pragma unroll
        for (int off = 1; off < 16; off <<= 1) s += __shfl_xor(s, off, 16);
        if (j == 0) ws[(o >= 8) ? (WS_WV + o - 8) : (WS_WQ + o)] = s;
    } else {
        #pragma unroll
        for (int e = 0; e < 8; ++e)
            *(float4*)&ws[WS_ZACC + e * 1024 + t * 4] = make_float4(0.f, 0.f, 0.f, 0.f);
    }
}

// ---------------------------------------------------------------------------
// kC: Z partials over 64-row chunks (512 blocks).  (R14-exact)
__global__ __launch_bounds__(256) void kC(const float* __restrict__ q,
                                          float* __restrict__ ws) {
    const int blk = blockIdx.x;          // 512 blocks: b = blk>>7, chunk = blk&127
    const int b = blk >> 7, c = blk & 127;
    const int d = threadIdx.x;
    const float qmx = ws[WS_QMAX + b * D + d];
    const float qmn = ws[WS_QMIN + b * D + d];
    float a[H], cc[H], z[H];
    #pragma unroll
    for (int h = 0; h < H; ++h) {
        float wq_ = ws[WS_WQ + h];
        float M = (wq_ >= 0.f) ? wq_ * qmx : wq_ * qmn;  // max_s of wq*q[b,s,d]
        a[h] = wq_ * LOG2E;
        cc[h] = -M * LOG2E;
        z[h] = 0.f;
    }
    const float* qp = q + ((size_t)b * S + c * 64) * D + d;
    #pragma unroll 4
    for (int r = 0; r < 64; ++r) {
        float qv = qp[(size_t)r * D];
        #pragma unroll
        for (int h = 0; h < H; ++h) z[h] += E2(fmaf(qv, a[h], cc[h]));
    }
    #pragma unroll
    for (int h = 0; h < H; ++h)
        atomicAdd(&ws[WS_ZACC + (size_t)(b * H + h) * D + d], z[h]);
}

// ---------------------------------------------------------------------------
// kE v10: 1024 blocks x 32 rows — ONE shared kc prologue per 32 rows (2x
// amortization vs v6). Manually staged ILP keeps VGPR bounded (R11 lesson):
//   load q(grp0) -> prologue -> compute(grp0) -> load q(grp1) ->
//   reduce/store(grp0) -> compute(grp1) -> reduce/store(grp1).
// __launch_bounds__(256,6): 85-VGPR ceiling, body needs ~60-70 -> no spill.
__global__ __launch_bounds__(256, 6) void kE(const float* __restrict__ q,
                                             const float* __restrict__ ws,
                                             float* __restrict__ out) {
    __shared__ float kcs[H * D];          // [h][j][slice][c] = h*256+j*64+slice*4+c
    __shared__ float wvs[8];

    const int blk = blockIdx.x;           // 1024 = B * 256
    const int b = blk >> 8, tl = blk & 255;
    const int t = threadIdx.x, w = t >> 6, lane = t & 63;
    const int r = t >> 4, slice = t & 15;

    const float* qbase = q + ((size_t)b * S + tl * 32 + r) * D + slice * 16;

    // grp0 q loads issue first; HBM/L3 latency hides under the kc prologue
    const float4* qp0 = (const float4*)qbase;
    float4 q0 = qp0[0], q1 = qp0[1], q2 = qp0[2], q3 = qp0[3];

    // fused kD: kc[h][d=t] = -M*log2e - log2(Z); swizzled store (v6-exact)
    const int dst = ((t >> 2) & 3) * 64 + (t >> 4) * 4 + (t & 3);
    const float qmx = ws[WS_QMAX + b * D + t];
    const float qmn = ws[WS_QMIN + b * D + t];
    float a[H];
    #pragma unroll
    for (int h = 0; h < H; ++h) {
        const float wq_ = ws[WS_WQ + h];
        const float M = (wq_ >= 0.f) ? wq_ * qmx : wq_ * qmn;
        kcs[h * 256 + dst] = -M * LOG2E
            - __builtin_amdgcn_logf(ws[WS_ZACC + (size_t)(b * H + h) * D + t]);
        a[h] = wq_ * LOG2E;
    }
    if (t < 8) wvs[t] = ws[WS_WV + t];
    const float4 cv4 = *(const float4*)&ws[WS_CV + b * D + lane * 4];
    __syncthreads();

    const float4* kc4 = (const float4*)kcs;

    // ---- grp0 compute (consumes q0..q3, frees them) ----
    float p[H];
    #pragma unroll
    for (int h = 0; h < H; ++h) p[h] = 0.f;
    #pragma unroll
    for (int j = 0; j < 4; ++j) {
        const float4 qv = (j == 0) ? q0 : (j == 1) ? q1 : (j == 2) ? q2 : q3;
        #pragma unroll
        for (int h = 0; h < H; ++h) {
            const float4 k = kc4[h * 64 + j * 16 + slice];
            p[h] += (E2(fmaf(qv.x, a[h], k.x)) + E2(fmaf(qv.y, a[h], k.y)))
                  + (E2(fmaf(qv.z, a[h], k.z)) + E2(fmaf(qv.w, a[h], k.w)));
        }
    }

    // ---- grp1 q loads issue here; latency hides under grp0 reduce/store ----
    const float4* qp1 = (const float4*)(qbase + 16 * D);
    q0 = qp1[0]; q1 = qp1[1]; q2 = qp1[2]; q3 = qp1[3];

    // ---- grp0 reduce + epilogue ----
    #pragma unroll
    for (int st = 1; st < 16; st <<= 1) {
        #pragma unroll
        for (int h = 0; h < H; ++h) p[h] += __shfl_xor(p[h], st, 16);
    }
    float amax = -3.4e38f, amin = 3.4e38f;
    #pragma unroll
    for (int h = 0; h < H; ++h) {
        const float A = wvs[h] * p[h];
        amax = fmaxf(amax, A);
        amin = fminf(amin, A);
    }
    float* og0 = out + ((size_t)b * S + tl * 32 + w * 4) * D;
    #pragma unroll
    for (int rr = 0; rr < 4; ++rr) {
        const float am = __shfl(amax, rr * 16, 64);
        const float an = __shfl(amin, rr * 16, 64);
        float4 o;
        o.x = (cv4.x >= 0.f) ? cv4.x * am : cv4.x * an;
        o.y = (cv4.y >= 0.f) ? cv4.y * am : cv4.y * an;
        o.z = (cv4.z >= 0.f) ? cv4.z * am : cv4.z * an;
        o.w = (cv4.w >= 0.f) ? cv4.w * am : cv4.w * an;
        *(float4*)&og0[(size_t)rr * D + lane * 4] = o;
    }

    // ---- grp1 compute + reduce + epilogue ----
    #pragma unroll
    for (int h = 0; h < H; ++h) p[h] = 0.f;
    #pragma unroll
    for (int j = 0; j < 4; ++j) {
        const float4 qv = (j == 0) ? q0 : (j == 1) ? q1 : (j == 2) ? q2 : q3;
        #pragma unroll
        for (int h = 0; h < H; ++h) {
            const float4 k = kc4[h * 64 + j * 16 + slice];
            p[h] += (E2(fmaf(qv.x, a[h], k.x)) + E2(fmaf(qv.y, a[h], k.y)))
                  + (E2(fmaf(qv.z, a[h], k.z)) + E2(fmaf(qv.w, a[h], k.w)));
        }
    }
    #pragma unroll
    for (int st = 1; st < 16; st <<= 1) {
        #pragma unroll
        for (int h = 0; h < H; ++h) p[h] += __shfl_xor(p[h], st, 16);
    }
    amax = -3.4e38f; amin = 3.4e38f;
    #pragma unroll
    for (int h = 0; h < H; ++h) {
        const float A = wvs[h] * p[h];
        amax = fmaxf(amax, A);
        amin = fminf(amin, A);
    }
    float* og1 = out + ((size_t)b * S + tl * 32 + 16 + w * 4) * D;
    #pragma unroll
    for (int rr = 0; rr < 4; ++rr) {
        const float am = __shfl(amax, rr * 16, 64);
        const float an = __shfl(amin, rr * 16, 64);
        float4 o;
        o.x = (cv4.x >= 0.f) ? cv4.x * am : cv4.x * an;
        o.y = (cv4.y >= 0.f) ? cv4.y * am : cv4.y * an;
        o.z = (cv4.z >= 0.f) ? cv4.z * am : cv4.z * an;
        o.w = (cv4.w >= 0.f) ? cv4.w * am : cv4.w * an;
        *(float4*)&og1[(size_t)rr * D + lane * 4] = o;
    }
}

// ---------------------------------------------------------------------------
extern "C" void kernel_launch(void* const* d_in, const int* in_sizes, int n_in,
                              void* d_out, int out_size, void* d_ws, size_t ws_size,
                              hipStream_t stream) {
    const float* q  = (const float*)d_in[0];
    // d_in[1] (k) and d_in[4] (k_weights) are provably unused: softmax over s sums to 1.
    const float* v  = (const float*)d_in[2];
    const float* qw = (const float*)d_in[3];
    const float* vw = (const float*)d_in[5];
    float* out = (float*)d_out;
    float* ws  = (float*)d_ws;

    kA<<<B * NT + 256, 256, 0, stream>>>(q, v, qw, vw, ws);
    kB<<<34, 256, 0, stream>>>(ws);
    kC<<<512, 256, 0, stream>>>(q, ws);
    kE<<<B * 256, 256, 0, stream>>>(q, ws, out);
}

// Round 18
// 51.516 us; speedup vs baseline: 3.4283x; 3.4283x over previous
//
#include <hip/hip_runtime.h>

// Problem constants
#define B 4
#define S 8192
#define D 256
#define H 8
#define NT 128               // col-stat tiles per batch (kA), 64 rows each
#define LOG2E 1.4426950408889634f
#define E2(x) __builtin_amdgcn_exp2f(x)

// Workspace layout (float offsets)
#define WS_WQ    0
#define WS_WV    8
#define WS_QMAX  16
#define WS_QMIN  (WS_QMAX + B*D)
#define WS_CV    (WS_QMIN + B*D)
#define WS_ZACC  (WS_CV + B*D)          // B*H*D
#define WS_WP    (WS_ZACC + B*H*D)      // 1024 weight partials
#define WS_P1    (WS_WP + 1024)
#define WS_P2    (WS_P1 + B*NT*D)
#define WS_P3    (WS_P2 + B*NT*D)

// ---------------------------------------------------------------------------
// kA: blocks [0,512): per-tile col stats of q (max/min) and v (sum).
//     blocks [512,768): weight-chunk partial sums.  (R14-exact)
__global__ __launch_bounds__(256) void kA(const float* __restrict__ q,
                                          const float* __restrict__ v,
                                          const float* __restrict__ qw,
                                          const float* __restrict__ vw,
                                          float* __restrict__ ws) {
    const int blk = blockIdx.x;
    const int t = threadIdx.x, w = t >> 6, lane = t & 63;

    if (blk >= B * NT) {                       // weight partials
        const int i = blk - B * NT;            // 0..255: which=i>>7, h=(i>>4)&7, ch=i&15
        const float4* src = (const float4*)(((i >> 7) ? vw : qw)
                              + (size_t)((i >> 4) & 7) * D * D) + (i & 15) * 1024;
        float sm = 0.f;
        #pragma unroll
        for (int j = 0; j < 4; ++j) {
            float4 a4 = src[j * 256 + t];
            sm += (a4.x + a4.y) + (a4.z + a4.w);
        }
        #pragma unroll
        for (int off = 32; off; off >>= 1) sm += __shfl_down(sm, off, 64);
        if (lane == 0) ws[WS_WP + i * 4 + w] = sm;
        return;
    }

    const int b = blk >> 7, tl = blk & (NT - 1);
    const int g = lane >> 4, cl = lane & 15;
    const int cblk = w * 16 + cl;              // 16B col block, 0..63
    const float4* qbase = (const float4*)(q + ((size_t)b * S + tl * 64) * D);
    const float4* vbase = (const float4*)(v + ((size_t)b * S + tl * 64) * D);
    float4 qmx = make_float4(-3.4e38f, -3.4e38f, -3.4e38f, -3.4e38f);
    float4 qmn = make_float4(3.4e38f, 3.4e38f, 3.4e38f, 3.4e38f);
    float4 vs = make_float4(0.f, 0.f, 0.f, 0.f);
    #pragma unroll 4
    for (int i = 0; i < 16; ++i) {
        const int row = i * 4 + g;
        float4 a4 = qbase[row * 64 + cblk];
        qmx.x = fmaxf(qmx.x, a4.x); qmx.y = fmaxf(qmx.y, a4.y);
        qmx.z = fmaxf(qmx.z, a4.z); qmx.w = fmaxf(qmx.w, a4.w);
        qmn.x = fminf(qmn.x, a4.x); qmn.y = fminf(qmn.y, a4.y);
        qmn.z = fminf(qmn.z, a4.z); qmn.w = fminf(qmn.w, a4.w);
        float4 b4 = vbase[row * 64 + cblk];
        vs.x += b4.x; vs.y += b4.y; vs.z += b4.z; vs.w += b4.w;
    }
    #pragma unroll
    for (int off = 16; off <= 32; off <<= 1) {
        qmx.x = fmaxf(qmx.x, __shfl_xor(qmx.x, off, 64));
        qmx.y = fmaxf(qmx.y, __shfl_xor(qmx.y, off, 64));
        qmx.z = fmaxf(qmx.z, __shfl_xor(qmx.z, off, 64));
        qmx.w = fmaxf(qmx.w, __shfl_xor(qmx.w, off, 64));
        qmn.x = fminf(qmn.x, __shfl_xor(qmn.x, off, 64));
        qmn.y = fminf(qmn.y, __shfl_xor(qmn.y, off, 64));
        qmn.z = fminf(qmn.z, __shfl_xor(qmn.z, off, 64));
        qmn.w = fminf(qmn.w, __shfl_xor(qmn.w, off, 64));
        vs.x += __shfl_xor(vs.x, off, 64);
        vs.y += __shfl_xor(vs.y, off, 64);
        vs.z += __shfl_xor(vs.z, off, 64);
        vs.w += __shfl_xor(vs.w, off, 64);
    }
    if (g == 0) {
        size_t pi = (size_t)(b * NT + tl) * D + cblk * 4;
        *(float4*)&ws[WS_P1 + pi] = qmx;
        *(float4*)&ws[WS_P2 + pi] = qmn;
        *(float4*)&ws[WS_P3 + pi] = vs;
    }
}

// ---------------------------------------------------------------------------
// kB: blocks 0..31 finish col stats; block 32 finishes weight sums;
//     block 33 zeroes the Z accumulators.  (R14-exact)
__global__ __launch_bounds__(256) void kB(float* __restrict__ ws) {
    const int blk = blockIdx.x, t = threadIdx.x;
    if (blk < 32) {
        const int bb = blk >> 3, oct = blk & 7;
        const int dl = t >> 3, sub = t & 7;
        const int d = oct * 32 + dl;
        float mx = -3.4e38f, mn = 3.4e38f, sm = 0.f;
        #pragma unroll 4
        for (int i = 0; i < 16; ++i) {
            size_t idx = (size_t)(bb * NT + sub * 16 + i) * D + d;
            mx = fmaxf(mx, ws[WS_P1 + idx]);
            mn = fminf(mn, ws[WS_P2 + idx]);
            sm += ws[WS_P3 + idx];
        }
        #pragma unroll
        for (int off = 1; off < 8; off <<= 1) {
            mx = fmaxf(mx, __shfl_xor(mx, off, 64));
            mn = fminf(mn, __shfl_xor(mn, off, 64));
            sm += __shfl_xor(sm, off, 64);
        }
        if (sub == 0) {
            ws[WS_QMAX + bb * D + d] = mx;
            ws[WS_QMIN + bb * D + d] = mn;
            ws[WS_CV + bb * D + d] = sm * (float)D;
        }
    } else if (blk == 32) {
        const int o = t >> 4, j = t & 15;        // o: 0..15 = (which,h)
        float s = 0.f;
        #pragma unroll
        for (int ww = 0; ww < 4; ++ww) s += ws[WS_WP + (o * 16 + j) * 4 + ww];
        #pragma unroll
        for (int off = 1; off < 16; off <<= 1) s += __shfl_xor(s, off, 16);
        if (j == 0) ws[(o >= 8) ? (WS_WV + o - 8) : (WS_WQ + o)] = s;
    } else {
        #pragma unroll
        for (int e = 0; e < 8; ++e)
            *(float4*)&ws[WS_ZACC + e * 1024 + t * 4] = make_float4(0.f, 0.f, 0.f, 0.f);
    }
}

// ---------------------------------------------------------------------------
// kC: Z partials over 64-row chunks (512 blocks).  (R14-exact)
__global__ __launch_bounds__(256) void kC(const float* __restrict__ q,
                                          float* __restrict__ ws) {
    const int blk = blockIdx.x;          // 512 blocks: b = blk>>7, chunk = blk&127
    const int b = blk >> 7, c = blk & 127;
    const int d = threadIdx.x;
    const float qmx = ws[WS_QMAX + b * D + d];
    const float qmn = ws[WS_QMIN + b * D + d];
    float a[H], cc[H], z[H];
    #pragma unroll
    for (int h = 0; h < H; ++h) {
        float wq_ = ws[WS_WQ + h];
        float M = (wq_ >= 0.f) ? wq_ * qmx : wq_ * qmn;  // max_s of wq*q[b,s,d]
        a[h] = wq_ * LOG2E;
        cc[h] = -M * LOG2E;
        z[h] = 0.f;
    }
    const float* qp = q + ((size_t)b * S + c * 64) * D + d;
    #pragma unroll 4
    for (int r = 0; r < 64; ++r) {
        float qv = qp[(size_t)r * D];
        #pragma unroll
        for (int h = 0; h < H; ++h) z[h] += E2(fmaf(qv, a[h], cc[h]));
    }
    #pragma unroll
    for (int h = 0; h < H; ++h)
        atomicAdd(&ws[WS_ZACC + (size_t)(b * H + h) * D + d], z[h]);
}

// ---------------------------------------------------------------------------
// kE v6 body (R14-exact) with the ONLY change: no min-waves hint. The (256,8)
// hint is a hard 64-VGPR clamp; this body is borderline (~60-70 live) and the
// clamp either spills a few regs or straitjackets scheduling. Natural
// allocation (~70-85) runs at 6 waves/SIMD with full scheduling freedom.
// 2048 blocks x 16 rows; kc fused into prologue (swizzled LDS);
// conflict-free float4 LDS reads; 4-step shfl_xor(16) reduce; barrier-free
// wave epilogue; wave-contiguous 1KB stores.
__global__ __launch_bounds__(256) void kE(const float* __restrict__ q,
                                          const float* __restrict__ ws,
                                          float* __restrict__ out) {
    __shared__ float kcs[H * D];          // [h][j][slice][c] = h*256+j*64+slice*4+c
    __shared__ float wvs[8];

    const int blk = blockIdx.x;           // 2048 = B * 512
    const int b = blk >> 9, tl = blk & 511;
    const int t = threadIdx.x, w = t >> 6, lane = t & 63;
    const int r = t >> 4, slice = t & 15;

    // issue q loads first; HBM latency hides under the kc prologue
    const float4* qp = (const float4*)(q + ((size_t)b * S + tl * 16 + r) * D
                                       + slice * 16);
    const float4 q0 = qp[0], q1 = qp[1], q2 = qp[2], q3 = qp[3];

    // fused kD: kc[h][d=t] = -M*log2e - log2(Z); swizzled store
    const int dst = ((t >> 2) & 3) * 64 + (t >> 4) * 4 + (t & 3);
    const float qmx = ws[WS_QMAX + b * D + t];
    const float qmn = ws[WS_QMIN + b * D + t];
    float a[H];
    #pragma unroll
    for (int h = 0; h < H; ++h) {
        const float wq_ = ws[WS_WQ + h];
        const float M = (wq_ >= 0.f) ? wq_ * qmx : wq_ * qmn;
        kcs[h * 256 + dst] = -M * LOG2E
            - __builtin_amdgcn_logf(ws[WS_ZACC + (size_t)(b * H + h) * D + t]);
        a[h] = wq_ * LOG2E;
    }
    if (t < 8) wvs[t] = ws[WS_WV + t];
    const float4 cv4 = *(const float4*)&ws[WS_CV + b * D + lane * 4];
    __syncthreads();

    float p[H];
    #pragma unroll
    for (int h = 0; h < H; ++h) p[h] = 0.f;

    const float4* kc4 = (const float4*)kcs;
    #pragma unroll
    for (int j = 0; j < 4; ++j) {
        const float4 qv = (j == 0) ? q0 : (j == 1) ? q1 : (j == 2) ? q2 : q3;
        #pragma unroll
        for (int h = 0; h < H; ++h) {
            const float4 k = kc4[h * 64 + j * 16 + slice];
            p[h] += (E2(fmaf(qv.x, a[h], k.x)) + E2(fmaf(qv.y, a[h], k.y)))
                  + (E2(fmaf(qv.z, a[h], k.z)) + E2(fmaf(qv.w, a[h], k.w)));
        }
    }
    #pragma unroll
    for (int st = 1; st < 16; st <<= 1) {
        #pragma unroll
        for (int h = 0; h < H; ++h) p[h] += __shfl_xor(p[h], st, 16);
    }
    float amax = -3.4e38f, amin = 3.4e38f;
    #pragma unroll
    for (int h = 0; h < H; ++h) {
        const float A = wvs[h] * p[h];    // uniform LDS broadcast
        amax = fmaxf(amax, A);
        amin = fminf(amin, A);
    }

    // barrier-free epilogue: rows w*4+rr were reduced within this wave,
    // their amax/amin live (replicated) in lanes rr*16..rr*16+15.
    float* og = out + ((size_t)b * S + tl * 16 + w * 4) * D;
    #pragma unroll
    for (int rr = 0; rr < 4; ++rr) {
        const float am = __shfl(amax, rr * 16, 64);
        const float an = __shfl(amin, rr * 16, 64);
        float4 o;
        o.x = (cv4.x >= 0.f) ? cv4.x * am : cv4.x * an;
        o.y = (cv4.y >= 0.f) ? cv4.y * am : cv4.y * an;
        o.z = (cv4.z >= 0.f) ? cv4.z * am : cv4.z * an;
        o.w = (cv4.w >= 0.f) ? cv4.w * am : cv4.w * an;
        *(float4*)&og[(size_t)rr * D + lane * 4] = o;  // 1KB/wave contiguous
    }
}

// ---------------------------------------------------------------------------
extern "C" void kernel_launch(void* const* d_in, const int* in_sizes, int n_in,
                              void* d_out, int out_size, void* d_ws, size_t ws_size,
                              hipStream_t stream) {
    const float* q  = (const float*)d_in[0];
    // d_in[1] (k) and d_in[4] (k_weights) are provably unused: softmax over s sums to 1.
    const float* v  = (const float*)d_in[2];
    const float* qw = (const float*)d_in[3];
    const float* vw = (const float*)d_in[5];
    float* out = (float*)d_out;
    float* ws  = (float*)d_ws;

    kA<<<B * NT + 256, 256, 0, stream>>>(q, v, qw, vw, ws);
    kB<<<34, 256, 0, stream>>>(ws);
    kC<<<512, 256, 0, stream>>>(q, ws);
    kE<<<B * 512, 256, 0, stream>>>(q, ws, out);
}